// Round 4
// baseline (1205.557 us; speedup 1.0000x reference)
//
#include <hip/hip_runtime.h>
#include <math.h>

#define EPSV 1e-12f
#define BALLC (1.0f - 1e-6f)
#define MAXT 15.0f
#define NBLK 512
#define BT 512

// ws layout (floats)
#define WS_MU 0
#define WS_P 128
#define WS_Q 256
#define WS_SC 384
#define WS_CTR 448   /* 32 int counters */
#define WS_HDR 512
#define S_MM 0
#define S_PP 1
#define S_QQ 2
#define S_MP 3
#define S_MQ 4
#define S_PQ 5
#define S_TFM 6
#define S_LAMP 7
#define S_KS 8
#define S_FLAG 9

__device__ __forceinline__ float fast_atanh(float x) {
    return 0.5f * __logf((1.f + x) / (1.f - x));
}
__device__ __forceinline__ float fast_tanh(float x) {
    float e = __expf(-2.f * x);
    return (1.f - e) / (1.f + e);
}
__device__ __forceinline__ float qsum4(float v) {
    v += __shfl_xor(v, 1);
    v += __shfl_xor(v, 2);
    return v;
}
__device__ __forceinline__ unsigned pack2_bf16(float a, float b) {
    unsigned ua = __float_as_uint(a), ub = __float_as_uint(b);
    ua += 0x7FFFu + ((ua >> 16) & 1u);
    ub += 0x7FFFu + ((ub >> 16) & 1u);
    return (ua >> 16) | (ub & 0xFFFF0000u);
}
__device__ __forceinline__ float lo_bf16(unsigned u) { return __uint_as_float(u << 16); }
__device__ __forceinline__ float hi_bf16(unsigned u) { return __uint_as_float(u & 0xFFFF0000u); }

// TREE over 128 slots; ALL threads of the block must execute it (barriers).
#define TREE(val, outv)                                       \
    if (tid < 128) lred[tid] = (val);                         \
    __syncthreads();                                          \
    for (int off = 64; off >= 1; off >>= 1) {                 \
        if (tid < off) lred[tid] += lred[tid + off];          \
        __syncthreads();                                      \
    }                                                         \
    outv = lred[0];                                           \
    __syncthreads();

__global__ void k_zero(float* ws) {
    int t = threadIdx.x;
    int* c = (int*)(ws + WS_CTR);
    if (t < 32) c[t] = 0;
    if (t == 32) ws[WS_SC + S_FLAG] = 0.f;
}

// ---------------------------------------------------------------------------
// Fused Karcher pass + last-block mu update.
// mode: 1 = first pass (mu=0), fp32 read + bf16 store
//       3 = first pass (mu=0), fp32 read, no store
//       2 = bf16 read      0 = fp32 read
// ---------------------------------------------------------------------------
__global__ __launch_bounds__(BT) void k_pass(const float* __restrict__ x,
                                             uint4* __restrict__ xb,
                                             float* __restrict__ ws,
                                             float* __restrict__ part,
                                             float* __restrict__ alpha,
                                             const int N, const int nblk,
                                             const float invN, const int mode,
                                             const int ctr) {
    const bool first = (mode == 1) || (mode == 3);
    if (!first && *(volatile const float*)(ws + WS_SC + S_FLAG) != 0.f) return;
    const int tid = threadIdx.x;
    const int lane = tid & 63;
    const int wv = tid >> 6;  // 0..7
    const int q4 = lane & 3;
    const int gid = blockIdx.x * (BT / 4) + (tid >> 2);
    const int gstride = nblk * (BT / 4);

    float mm = 0.f, tfm = 1.f;
    float4 mur[8];
#pragma unroll
    for (int k = 0; k < 8; ++k) mur[k] = make_float4(0.f, 0.f, 0.f, 0.f);
    if (!first) {
        mm = ws[WS_SC + S_MM];
        tfm = fmaxf(1.f - mm, EPSV);
        const float4* mu4 = (const float4*)(ws + WS_MU);
#pragma unroll
        for (int k = 0; k < 4; ++k) {
            int o = 4 * k + q4;
            mur[2 * k] = mu4[o * 2];
            mur[2 * k + 1] = mu4[o * 2 + 1];
        }
    }
    float4 acc[8];
#pragma unroll
    for (int k = 0; k < 8; ++k) acc[k] = make_float4(0.f, 0.f, 0.f, 0.f);
    float accA = 0.f;

    for (int row = gid; row < N; row += gstride) {
        float4 xv[8];
        if (mode == 2) {
            const uint4* xbr = xb + (size_t)row * 16;
#pragma unroll
            for (int k = 0; k < 4; ++k) {
                uint4 u = xbr[4 * k + q4];
                xv[2 * k].x = lo_bf16(u.x); xv[2 * k].y = hi_bf16(u.x);
                xv[2 * k].z = lo_bf16(u.y); xv[2 * k].w = hi_bf16(u.y);
                xv[2 * k + 1].x = lo_bf16(u.z); xv[2 * k + 1].y = hi_bf16(u.z);
                xv[2 * k + 1].z = lo_bf16(u.w); xv[2 * k + 1].w = hi_bf16(u.w);
            }
        } else {
            const float4* xr = (const float4*)(x + (size_t)row * 128);
#pragma unroll
            for (int k = 0; k < 4; ++k) {
                int o = 4 * k + q4;
                xv[2 * k] = xr[o * 2];
                xv[2 * k + 1] = xr[o * 2 + 1];
            }
            if (mode == 1) {
                uint4* xbr = xb + (size_t)row * 16;
#pragma unroll
                for (int k = 0; k < 4; ++k) {
                    uint4 u;
                    u.x = pack2_bf16(xv[2 * k].x, xv[2 * k].y);
                    u.y = pack2_bf16(xv[2 * k].z, xv[2 * k].w);
                    u.z = pack2_bf16(xv[2 * k + 1].x, xv[2 * k + 1].y);
                    u.w = pack2_bf16(xv[2 * k + 1].z, xv[2 * k + 1].w);
                    xbr[4 * k + q4] = u;
                }
            }
        }
        float dp = 0.f, np = 0.f;
#pragma unroll
        for (int k = 0; k < 8; ++k) {
            dp += mur[k].x * xv[k].x + mur[k].y * xv[k].y + mur[k].z * xv[k].z + mur[k].w * xv[k].w;
            np += xv[k].x * xv[k].x + xv[k].y * xv[k].y + xv[k].z * xv[k].z + xv[k].w * xv[k].w;
        }
        float d = first ? 0.f : qsum4(dp);
        float X2 = qsum4(np);
        float A = 1.f - 2.f * d + X2;
        float B = 1.f - mm;
        float den = fmaxf(1.f - 2.f * d + mm * X2, EPSV);
        float iv = 1.f / den;
        float m2 = (A * A * mm - 2.f * A * B * d + B * B * X2) * iv * iv;
        float n = sqrtf(fmaxf(m2, EPSV));
        float s = tfm * fast_atanh(fminf(n, BALLC)) / n;
        accA += s * (-A * iv);
        float delta = s * (B * iv);
#pragma unroll
        for (int k = 0; k < 8; ++k) {
            acc[k].x += delta * xv[k].x;
            acc[k].y += delta * xv[k].y;
            acc[k].z += delta * xv[k].z;
            acc[k].w += delta * xv[k].w;
        }
    }

#pragma unroll
    for (int m = 4; m < 64; m <<= 1) {
#pragma unroll
        for (int k = 0; k < 8; ++k) {
            acc[k].x += __shfl_xor(acc[k].x, m);
            acc[k].y += __shfl_xor(acc[k].y, m);
            acc[k].z += __shfl_xor(acc[k].z, m);
            acc[k].w += __shfl_xor(acc[k].w, m);
        }
        accA += __shfl_xor(accA, m);
    }
    __shared__ float lvec[8][128];
    __shared__ float lalpha[8];
    __shared__ float lred[128];
    __shared__ int amLast;
    if (lane < 4) {
#pragma unroll
        for (int k = 0; k < 4; ++k) {
            int o = 4 * k + lane;
#pragma unroll
            for (int h = 0; h < 2; ++h) {
                int c = o * 8 + 4 * h;
                float4 a = acc[2 * k + h];
                lvec[wv][c + 0] = a.x;
                lvec[wv][c + 1] = a.y;
                lvec[wv][c + 2] = a.z;
                lvec[wv][c + 3] = a.w;
            }
        }
    }
    if (lane == 0) lalpha[wv] = accA;
    __syncthreads();
    if (tid < 128) {
        float s = 0.f;
#pragma unroll
        for (int i = 0; i < 8; ++i) s += lvec[i][tid];
        part[(size_t)blockIdx.x * 132 + tid] = s;
    }
    if (tid == 0) {
        float a = 0.f;
#pragma unroll
        for (int i = 0; i < 8; ++i) a += lalpha[i];
        alpha[blockIdx.x] = a;
    }
    __syncthreads();
    if (tid == 0) {
        __threadfence();  // release this block's partials to device scope
        int* cp = (int*)(ws + WS_CTR);
        int prev = __hip_atomic_fetch_add(&cp[ctr], 1, __ATOMIC_ACQ_REL,
                                          __HIP_MEMORY_SCOPE_AGENT);
        amLast = (prev == nblk - 1);
    }
    __syncthreads();
    if (!amLast) return;
    __threadfence();  // acquire: every reducing thread sees fresh partials

    // ---- last block: reduce partials and update mu ----
    __shared__ float lsum[4][128];
    {
        int c = tid & 127, sg = tid >> 7;
        float s = 0.f;
        for (int b = sg; b < nblk; b += 4) s += part[(size_t)b * 132 + c];
        lsum[sg][c] = s;
    }
    float av = 0.f;
    if (tid < 128)
        for (int b = tid; b < nblk; b += 128) av += alpha[b];
    __syncthreads();
    float atot; TREE(av, atot);
    float mu_c = 0.f, v = 0.f;
    if (tid < 128) {
        float vs = lsum[0][tid] + lsum[1][tid] + lsum[2][tid] + lsum[3][tid];
        mu_c = first ? 0.f : ws[WS_MU + tid];
        v = (vs + atot * mu_c) * invN;
    }
    float v2; TREE(v * v, v2);
    float nv = sqrtf(fmaxf(v2, EPSV));
    float lam = 2.f / tfm;  // tfm = max(1-mm,EPS); mm==0 on first pass
    float arg = fminf(fmaxf(lam * nv * 0.5f, -MAXT), MAXT);
    float tt = fast_tanh(arg);
    float sec = tt * v / nv;
    float xy; TREE(mu_c * sec, xy);
    float s2n; TREE(sec * sec, s2n);
    float A = 1.f + 2.f * xy + s2n;
    float B = 1.f - mm;
    float den = fmaxf(1.f + 2.f * xy + mm * s2n, EPSV);
    float munew = (A * mu_c + B * sec) / den;
    float mm2; TREE(munew * munew, mm2);
    float df = munew - mu_c;
    float stepn2; TREE(df * df, stepn2);
    if (tid < 128) ws[WS_MU + tid] = munew;
    if (tid == 0) {
        ws[WS_SC + S_MM] = mm2;
        if (!first && stepn2 < 1e-10f) ws[WS_SC + S_FLAG] = 1.f;
    }
}

// ---------------------------------------------------------------------------
// Fused variance pass + last-block prep (p, q, Gram scalars, ks).
// ---------------------------------------------------------------------------
__global__ __launch_bounds__(BT) void k_varprep(const float* __restrict__ x,
                                                const uint4* __restrict__ xb,
                                                const float* __restrict__ mpar,
                                                const float* __restrict__ vpar,
                                                float* __restrict__ ws,
                                                float* __restrict__ alpha,
                                                const int N, const int nblk,
                                                const float invN, const int rd16,
                                                const int ctr) {
    const int tid = threadIdx.x;
    const int lane = tid & 63;
    const int wv = tid >> 6;
    const int q4 = lane & 3;
    const int gid = blockIdx.x * (BT / 4) + (tid >> 2);
    const int gstride = nblk * (BT / 4);
    const float mm = ws[WS_SC + S_MM];
    const float4* mu4 = (const float4*)(ws + WS_MU);
    float4 mur[8];
#pragma unroll
    for (int k = 0; k < 4; ++k) {
        int o = 4 * k + q4;
        mur[2 * k] = mu4[o * 2];
        mur[2 * k + 1] = mu4[o * 2 + 1];
    }
    float accv = 0.f;
    for (int row = gid; row < N; row += gstride) {
        float4 xv[8];
        if (rd16) {
            const uint4* xbr = xb + (size_t)row * 16;
#pragma unroll
            for (int k = 0; k < 4; ++k) {
                uint4 u = xbr[4 * k + q4];
                xv[2 * k].x = lo_bf16(u.x); xv[2 * k].y = hi_bf16(u.x);
                xv[2 * k].z = lo_bf16(u.y); xv[2 * k].w = hi_bf16(u.y);
                xv[2 * k + 1].x = lo_bf16(u.z); xv[2 * k + 1].y = hi_bf16(u.z);
                xv[2 * k + 1].z = lo_bf16(u.w); xv[2 * k + 1].w = hi_bf16(u.w);
            }
        } else {
            const float4* xr = (const float4*)(x + (size_t)row * 128);
#pragma unroll
            for (int k = 0; k < 4; ++k) {
                int o = 4 * k + q4;
                xv[2 * k] = xr[o * 2];
                xv[2 * k + 1] = xr[o * 2 + 1];
            }
        }
        float dp = 0.f, np = 0.f;
#pragma unroll
        for (int k = 0; k < 8; ++k) {
            dp += mur[k].x * xv[k].x + mur[k].y * xv[k].y + mur[k].z * xv[k].z + mur[k].w * xv[k].w;
            np += xv[k].x * xv[k].x + xv[k].y * xv[k].y + xv[k].z * xv[k].z + xv[k].w * xv[k].w;
        }
        float d = qsum4(dp);
        float X2 = qsum4(np);
        float A = 1.f - 2.f * d + X2;
        float B = 1.f - mm;
        float den = fmaxf(1.f - 2.f * d + mm * X2, EPSV);
        float iv = 1.f / den;
        float m2 = (A * A * mm - 2.f * A * B * d + B * B * X2) * iv * iv;
        float n = sqrtf(fmaxf(m2, EPSV));
        float dist = 2.f * fast_atanh(fminf(n, BALLC));
        accv += dist * dist;
    }
#pragma unroll
    for (int m = 4; m < 64; m <<= 1) accv += __shfl_xor(accv, m);
    __shared__ float lsc[8];
    __shared__ float lred[128];
    __shared__ int amLast;
    if (lane == 0) lsc[wv] = accv;
    __syncthreads();
    if (tid == 0) {
        float a = 0.f;
#pragma unroll
        for (int i = 0; i < 8; ++i) a += lsc[i];
        alpha[blockIdx.x] = a;
    }
    __syncthreads();
    if (tid == 0) {
        __threadfence();
        int* cp = (int*)(ws + WS_CTR);
        int prev = __hip_atomic_fetch_add(&cp[ctr], 1, __ATOMIC_ACQ_REL,
                                          __HIP_MEMORY_SCOPE_AGENT);
        amLast = (prev == nblk - 1);
    }
    __syncthreads();
    if (!amLast) return;
    __threadfence();

    // ---- last block: variance + p/q/Gram prep ----
    float vsum = 0.f;
    if (tid < 128)
        for (int b = tid; b < nblk; b += 128) vsum += alpha[b];
    __syncthreads();
    float varsum; TREE(vsum, varsum);
    float input_var = varsum * invN;
    float mpv = (tid < 128) ? mpar[tid] : 0.f;
    float mpn2; TREE(mpv * mpv, mpn2);
    float pn = sqrtf(fmaxf(mpn2, EPSV));
    float p_c = fast_tanh(pn) * mpv / pn;
    float pp; TREE(p_c * p_c, pp);
    float mu_c = (tid < 128) ? ws[WS_MU + tid] : 0.f;
    float pm; TREE(p_c * mu_c, pm);
    float A = 1.f - 2.f * pm + mm;
    float B = 1.f - pp;
    float den = fmaxf(1.f - 2.f * pm + pp * mm, EPSV);
    float q_c = (B * mu_c - A * p_c) / den;
    float qq; TREE(q_c * q_c, qq);
    float mq; TREE(mu_c * q_c, mq);
    float pq; TREE(p_c * q_c, pq);
    float tfm = fmaxf(1.f - mm, EPSV);
    float tfp = fmaxf(1.f - pp, EPSV);
    float lam_p = 2.f / tfp;
    float svar = sqrtf(vpar[0] / (input_var + 1e-6f));
    float ks = (tfp / tfm) * svar;
    if (tid < 128) {
        ws[WS_P + tid] = p_c;
        ws[WS_Q + tid] = q_c;
    }
    if (tid == 0) {
        ws[WS_SC + S_PP] = pp; ws[WS_SC + S_QQ] = qq; ws[WS_SC + S_MP] = pm;
        ws[WS_SC + S_MQ] = mq; ws[WS_SC + S_PQ] = pq; ws[WS_SC + S_TFM] = tfm;
        ws[WS_SC + S_LAMP] = lam_p; ws[WS_SC + S_KS] = ks;
    }
}

// final pass: out_i = expmap(p, ks * gyr(p,-mu, logmap(mu,x_i)))
__global__ __launch_bounds__(BT) void k_out(const float* __restrict__ x,
                                            float* __restrict__ out,
                                            const float* __restrict__ ws,
                                            const int N, const int nblk) {
    const float mm = ws[WS_SC + S_MM], pp = ws[WS_SC + S_PP], qq = ws[WS_SC + S_QQ];
    const float smp = ws[WS_SC + S_MP], smq = ws[WS_SC + S_MQ], spq = ws[WS_SC + S_PQ];
    const float tfm = ws[WS_SC + S_TFM], lam_p = ws[WS_SC + S_LAMP], ks = ws[WS_SC + S_KS];
    const int tid = threadIdx.x;
    const int lane = tid & 63;
    const int q4 = lane & 3;
    const int gid = blockIdx.x * (BT / 4) + (tid >> 2);
    const int gstride = nblk * (BT / 4);
    const float4* mu4 = (const float4*)(ws + WS_MU);
    const float4* p4 = (const float4*)(ws + WS_P);
    const float4* qv4 = (const float4*)(ws + WS_Q);
    float4 mur[8], pr[8], qr[8];
#pragma unroll
    for (int k = 0; k < 4; ++k) {
        int o = 4 * k + q4;
        mur[2 * k] = mu4[o * 2];   mur[2 * k + 1] = mu4[o * 2 + 1];
        pr[2 * k] = p4[o * 2];     pr[2 * k + 1] = p4[o * 2 + 1];
        qr[2 * k] = qv4[o * 2];    qr[2 * k + 1] = qv4[o * 2 + 1];
    }
    for (int row = gid; row < N; row += gstride) {
        const float4* xr = (const float4*)(x + (size_t)row * 128);
        float4 xv[8];
#pragma unroll
        for (int k = 0; k < 4; ++k) {
            int o = 4 * k + q4;
            xv[2 * k] = xr[o * 2];
            xv[2 * k + 1] = xr[o * 2 + 1];
        }
        float am = 0.f, ap = 0.f, aq = 0.f, an = 0.f;
#pragma unroll
        for (int k = 0; k < 8; ++k) {
            am += mur[k].x * xv[k].x + mur[k].y * xv[k].y + mur[k].z * xv[k].z + mur[k].w * xv[k].w;
            ap += pr[k].x * xv[k].x + pr[k].y * xv[k].y + pr[k].z * xv[k].z + pr[k].w * xv[k].w;
            aq += qr[k].x * xv[k].x + qr[k].y * xv[k].y + qr[k].z * xv[k].z + qr[k].w * xv[k].w;
            an += xv[k].x * xv[k].x + xv[k].y * xv[k].y + xv[k].z * xv[k].z + xv[k].w * xv[k].w;
        }
        float Dm = qsum4(am), Dp = qsum4(ap), Dq = qsum4(aq), X2 = qsum4(an);

        float A = 1.f - 2.f * Dm + X2;
        float B = 1.f - mm;
        float den = fmaxf(1.f - 2.f * Dm + mm * X2, EPSV);
        float iv = 1.f / den;
        float m_cm = -A * iv, m_cx = B * iv;
        float m_dm = (-A * mm + B * Dm) * iv;
        float m_dp = (-A * smp + B * Dp) * iv;
        float m_dq = (-A * smq + B * Dq) * iv;
        float m_n2 = (A * A * mm - 2.f * A * B * Dm + B * B * X2) * iv * iv;

        float n1 = sqrtf(fmaxf(m_n2, EPSV));
        float s1 = tfm * fast_atanh(fminf(n1, BALLC)) / n1;
        float t_cm = s1 * m_cm, t_cx = s1 * m_cx;
        float t_dm = s1 * m_dm, t_dp = s1 * m_dp, t_dq = s1 * m_dq;
        float t_n2 = s1 * s1 * m_n2;

        float xy = -t_dm, y2 = t_n2;
        A = 1.f + 2.f * xy + y2;
        B = 1.f - mm;
        den = fmaxf(1.f + 2.f * xy + mm * y2, EPSV);
        iv = 1.f / den;
        float w_cm = (-A + B * t_cm) * iv;
        float w_cx = B * t_cx * iv;
        float w_dp = (-A * smp + B * t_dp) * iv;
        float w_dq = (-A * smq + B * t_dq) * iv;
        float w_n2 = (A * A * mm + 2.f * A * B * xy + B * B * y2) * iv * iv;

        xy = w_dp; y2 = w_n2;
        A = 1.f + 2.f * xy + y2;
        B = 1.f - pp;
        den = fmaxf(1.f + 2.f * xy + pp * y2, EPSV);
        iv = 1.f / den;
        float w2_cm = B * w_cm * iv;
        float w2_cp = A * iv;
        float w2_cx = B * w_cx * iv;
        float w2_dp = (A * pp + B * w_dp) * iv;
        float w2_dq = (A * spq + B * w_dq) * iv;
        float w2_n2 = (A * A * pp + 2.f * A * B * xy + B * B * y2) * iv * iv;

        xy = w2_dq; y2 = w2_n2;
        A = 1.f + 2.f * xy + y2;
        B = 1.f - qq;
        den = fmaxf(1.f + 2.f * xy + qq * y2, EPSV);
        iv = 1.f / den;
        float w3_cm = B * w2_cm * iv;
        float w3_cp = B * w2_cp * iv;
        float w3_cq = A * iv;
        float w3_cx = B * w2_cx * iv;
        float w3_dp = (A * spq + B * w2_dp) * iv;
        float w3_n2 = (A * A * qq + 2.f * A * B * xy + B * B * y2) * iv * iv;

        float u_n2 = ks * ks * w3_n2;
        float nu = sqrtf(fmaxf(u_n2, EPSV));
        float arg = fminf(fmaxf(lam_p * nu * 0.5f, -MAXT), MAXT);
        float sf = fast_tanh(arg) * ks / nu;
        float s_cm = sf * w3_cm, s_cp = sf * w3_cp, s_cq = sf * w3_cq, s_cx = sf * w3_cx;
        float s_dp = sf * w3_dp;
        float s_n2 = sf * sf * w3_n2;

        xy = s_dp; y2 = s_n2;
        A = 1.f + 2.f * xy + y2;
        B = 1.f - pp;
        den = fmaxf(1.f + 2.f * xy + pp * y2, EPSV);
        iv = 1.f / den;
        float o_cm = B * s_cm * iv;
        float o_cp = (A + B * s_cp) * iv;
        float o_cq = B * s_cq * iv;
        float o_cx = B * s_cx * iv;

        float4* orow = (float4*)(out + (size_t)row * 128);
#pragma unroll
        for (int k = 0; k < 4; ++k) {
            int o = 4 * k + q4;
#pragma unroll
            for (int h = 0; h < 2; ++h) {
                float4 xvk = xv[2 * k + h];
                float4 mk = mur[2 * k + h], pk = pr[2 * k + h], qk = qr[2 * k + h];
                float4 ov;
                ov.x = o_cm * mk.x + o_cp * pk.x + o_cq * qk.x + o_cx * xvk.x;
                ov.y = o_cm * mk.y + o_cp * pk.y + o_cq * qk.y + o_cx * xvk.y;
                ov.z = o_cm * mk.z + o_cp * pk.z + o_cq * qk.z + o_cx * xvk.z;
                ov.w = o_cm * mk.w + o_cp * pk.w + o_cq * qk.w + o_cx * xvk.w;
                orow[o * 2 + h] = ov;
            }
        }
    }
}

extern "C" void kernel_launch(void* const* d_in, const int* in_sizes, int n_in,
                              void* d_out, int out_size, void* d_ws, size_t ws_size,
                              hipStream_t stream) {
    const float* x = (const float*)d_in[0];
    const float* mpar = (const float*)d_in[1];
    const float* vpar = (const float*)d_in[2];
    float* out = (float*)d_out;
    float* ws = (float*)d_ws;
    int N = in_sizes[0] / 128;
    float invN = 1.f / (float)N;

    long wsf = (long)(ws_size / sizeof(float));
    int nblk = NBLK;
    {
        long nb = (wsf - WS_HDR) / 133;
        if (nb < nblk) nblk = (nb < 8) ? 8 : (int)nb;
    }
    float* part = ws + WS_HDR;
    float* alpha = part + (long)nblk * 132;
    long off_xb = WS_HDR + (long)nblk * 133;
    off_xb = (off_xb + 3) & ~3L;  // 16B align
    uint4* xb = (uint4*)(ws + off_xb);
    int use16 = (ws_size >= (size_t)off_xb * sizeof(float) + (size_t)N * 256) ? 1 : 0;

    hipLaunchKernelGGL(k_zero, dim3(1), dim3(64), 0, stream, ws);
    // pass 0 (mu = 0, equals exp0(mean(log0 x)) init), converts x -> bf16 if room
    hipLaunchKernelGGL(k_pass, dim3(nblk), dim3(BT), 0, stream,
                       x, xb, ws, part, alpha, N, nblk, invN, use16 ? 1 : 3, 0);
    for (int it = 1; it < 16; ++it)
        hipLaunchKernelGGL(k_pass, dim3(nblk), dim3(BT), 0, stream,
                           x, xb, ws, part, alpha, N, nblk, invN, use16 ? 2 : 0, it);
    hipLaunchKernelGGL(k_varprep, dim3(nblk), dim3(BT), 0, stream,
                       x, xb, mpar, vpar, ws, alpha, N, nblk, invN, use16, 16);
    hipLaunchKernelGGL(k_out, dim3(nblk), dim3(BT), 0, stream, x, out, ws, N, nblk);
}

// Round 5
// 522.526 us; speedup vs baseline: 2.3072x; 2.3072x over previous
//
#include <hip/hip_runtime.h>
#include <math.h>

#define EPSV 1e-12f
#define BALLC (1.0f - 1e-6f)
#define MAXT 15.0f
#define NB0 512         // blocks for fp32-wide passes (pass0, k_out)
#define NB1 256         // blocks for bf16 passes (keeps k_upd's read small)
#define BT 512          // threads per block
#define STEP_TOL2 1e-8f // ||mu_{k+1}-mu_k||^2 early-out (step < 1e-4)

// ws layout (floats)
#define WS_MU 0
#define WS_P 128
#define WS_Q 256
#define WS_SC 384
#define WS_HDR 512
#define S_MM 0
#define S_PP 1
#define S_QQ 2
#define S_MP 3
#define S_MQ 4
#define S_PQ 5
#define S_TFM 6
#define S_LAMP 7
#define S_KS 8
#define S_FLAG 9

__device__ __forceinline__ float fast_atanh(float x) {
    return 0.5f * __logf((1.f + x) / (1.f - x));
}
__device__ __forceinline__ float fast_tanh(float x) {
    float e = __expf(-2.f * x);
    return (1.f - e) / (1.f + e);
}
__device__ __forceinline__ float qsum4(float v) {
    v += __shfl_xor(v, 1);
    v += __shfl_xor(v, 2);
    return v;
}
__device__ __forceinline__ unsigned pack2_bf16(float a, float b) {
    unsigned ua = __float_as_uint(a), ub = __float_as_uint(b);
    ua += 0x7FFFu + ((ua >> 16) & 1u);
    ub += 0x7FFFu + ((ub >> 16) & 1u);
    return (ua >> 16) | (ub & 0xFFFF0000u);
}
__device__ __forceinline__ float lo_bf16(unsigned u) { return __uint_as_float(u << 16); }
__device__ __forceinline__ float hi_bf16(unsigned u) { return __uint_as_float(u & 0xFFFF0000u); }

__global__ void k_zero(float* ws) {
    int t = threadIdx.x;
    if (t < 128) ws[WS_MU + t] = 0.f;
    if (t < 16) ws[WS_SC + t] = 0.f;  // includes S_MM and S_FLAG
}

// ---------------------------------------------------------------------------
// One Karcher pass. mode: 1 = first pass (mu=0), fp32 read + bf16 store
//                        3 = first pass (mu=0), fp32 read
//                        2 = bf16 read   0 = fp32 read
// Writes per-block partials: part[bid*132 + c] (vector) and alpha[bid].
// ---------------------------------------------------------------------------
__global__ __launch_bounds__(BT) void k_pass(const float* __restrict__ x,
                                             uint4* __restrict__ xb,
                                             const float* __restrict__ ws,
                                             float* __restrict__ part,
                                             float* __restrict__ alpha,
                                             const int N, const int mode) {
    const bool first = (mode == 1) || (mode == 3);
    if (!first && ws[WS_SC + S_FLAG] != 0.f) return;
    const int tid = threadIdx.x;
    const int lane = tid & 63;
    const int wv = tid >> 6;  // 0..7
    const int q4 = lane & 3;
    const int gid = blockIdx.x * (BT / 4) + (tid >> 2);
    const int gstride = gridDim.x * (BT / 4);

    float mm = 0.f, tfm = 1.f;
    float4 mur[8];
#pragma unroll
    for (int k = 0; k < 8; ++k) mur[k] = make_float4(0.f, 0.f, 0.f, 0.f);
    if (!first) {
        mm = ws[WS_SC + S_MM];
        tfm = fmaxf(1.f - mm, EPSV);
        const float4* mu4 = (const float4*)(ws + WS_MU);
#pragma unroll
        for (int k = 0; k < 4; ++k) {
            int o = 4 * k + q4;
            mur[2 * k] = mu4[o * 2];
            mur[2 * k + 1] = mu4[o * 2 + 1];
        }
    }
    float4 acc[8];
#pragma unroll
    for (int k = 0; k < 8; ++k) acc[k] = make_float4(0.f, 0.f, 0.f, 0.f);
    float accA = 0.f;

    for (int row = gid; row < N; row += gstride) {
        float4 xv[8];
        if (mode == 2) {
            const uint4* xbr = xb + (size_t)row * 16;
#pragma unroll
            for (int k = 0; k < 4; ++k) {
                uint4 u = xbr[4 * k + q4];
                xv[2 * k].x = lo_bf16(u.x); xv[2 * k].y = hi_bf16(u.x);
                xv[2 * k].z = lo_bf16(u.y); xv[2 * k].w = hi_bf16(u.y);
                xv[2 * k + 1].x = lo_bf16(u.z); xv[2 * k + 1].y = hi_bf16(u.z);
                xv[2 * k + 1].z = lo_bf16(u.w); xv[2 * k + 1].w = hi_bf16(u.w);
            }
        } else {
            const float4* xr = (const float4*)(x + (size_t)row * 128);
#pragma unroll
            for (int k = 0; k < 4; ++k) {
                int o = 4 * k + q4;
                xv[2 * k] = xr[o * 2];
                xv[2 * k + 1] = xr[o * 2 + 1];
            }
            if (mode == 1) {
                uint4* xbr = xb + (size_t)row * 16;
#pragma unroll
                for (int k = 0; k < 4; ++k) {
                    uint4 u;
                    u.x = pack2_bf16(xv[2 * k].x, xv[2 * k].y);
                    u.y = pack2_bf16(xv[2 * k].z, xv[2 * k].w);
                    u.z = pack2_bf16(xv[2 * k + 1].x, xv[2 * k + 1].y);
                    u.w = pack2_bf16(xv[2 * k + 1].z, xv[2 * k + 1].w);
                    xbr[4 * k + q4] = u;
                }
            }
        }
        float dp = 0.f, np = 0.f;
#pragma unroll
        for (int k = 0; k < 8; ++k) {
            dp += mur[k].x * xv[k].x + mur[k].y * xv[k].y + mur[k].z * xv[k].z + mur[k].w * xv[k].w;
            np += xv[k].x * xv[k].x + xv[k].y * xv[k].y + xv[k].z * xv[k].z + xv[k].w * xv[k].w;
        }
        float d = first ? 0.f : qsum4(dp);
        float X2 = qsum4(np);
        float A = 1.f - 2.f * d + X2;
        float B = 1.f - mm;
        float den = fmaxf(1.f - 2.f * d + mm * X2, EPSV);
        float iv = 1.f / den;
        float m2 = (A * A * mm - 2.f * A * B * d + B * B * X2) * iv * iv;
        float n = sqrtf(fmaxf(m2, EPSV));
        float s = tfm * fast_atanh(fminf(n, BALLC)) / n;
        accA += s * (-A * iv);
        float delta = s * (B * iv);
#pragma unroll
        for (int k = 0; k < 8; ++k) {
            acc[k].x += delta * xv[k].x;
            acc[k].y += delta * xv[k].y;
            acc[k].z += delta * xv[k].z;
            acc[k].w += delta * xv[k].w;
        }
    }

#pragma unroll
    for (int m = 4; m < 64; m <<= 1) {
#pragma unroll
        for (int k = 0; k < 8; ++k) {
            acc[k].x += __shfl_xor(acc[k].x, m);
            acc[k].y += __shfl_xor(acc[k].y, m);
            acc[k].z += __shfl_xor(acc[k].z, m);
            acc[k].w += __shfl_xor(acc[k].w, m);
        }
        accA += __shfl_xor(accA, m);
    }
    __shared__ float lvec[8][128];
    __shared__ float lalpha[8];
    if (lane < 4) {
#pragma unroll
        for (int k = 0; k < 4; ++k) {
            int o = 4 * k + lane;
#pragma unroll
            for (int h = 0; h < 2; ++h) {
                int c = o * 8 + 4 * h;
                float4 a = acc[2 * k + h];
                lvec[wv][c + 0] = a.x;
                lvec[wv][c + 1] = a.y;
                lvec[wv][c + 2] = a.z;
                lvec[wv][c + 3] = a.w;
            }
        }
    }
    if (lane == 0) lalpha[wv] = accA;
    __syncthreads();
    if (tid < 128) {
        float s = 0.f;
#pragma unroll
        for (int i = 0; i < 8; ++i) s += lvec[i][tid];
        part[(size_t)blockIdx.x * 132 + tid] = s;
    }
    if (tid == 0) {
        float a = 0.f;
#pragma unroll
        for (int i = 0; i < 8; ++i) a += lalpha[i];
        alpha[blockIdx.x] = a;
    }
}

// mu <- expmap(mu, mean_tangent); sets early-out flag when step is tiny.
__global__ __launch_bounds__(1024) void k_upd(float* __restrict__ ws,
                                              const float* __restrict__ part,
                                              const float* __restrict__ alpha,
                                              const int nblk, const float invN,
                                              const int isfirst) {
    if (!isfirst && ws[WS_SC + S_FLAG] != 0.f) return;
    __shared__ float lvec[8][128];
    __shared__ float lred[128];
    const int tid = threadIdx.x;
    const int c = tid & 127;
    const int sg = tid >> 7;
    float s = 0.f;
    for (int b = sg; b < nblk; b += 8) s += part[(size_t)b * 132 + c];  // coalesced
    lvec[sg][c] = s;
    __syncthreads();

#define TREE(val, outv)                                      \
    if (tid < 128) lred[tid] = (val);                        \
    __syncthreads();                                         \
    for (int off = 64; off >= 1; off >>= 1) {                \
        if (tid < off) lred[tid] += lred[tid + off];         \
        __syncthreads();                                     \
    }                                                        \
    outv = lred[0];                                          \
    __syncthreads();

    float av = 0.f;
    if (tid < 128)
        for (int b = tid; b < nblk; b += 128) av += alpha[b];
    float atot; TREE(av, atot);

    float mm = ws[WS_SC + S_MM];
    float mu_c = 0.f, v = 0.f;
    if (tid < 128) {
        float vs = 0.f;
#pragma unroll
        for (int i = 0; i < 8; ++i) vs += lvec[i][c];
        mu_c = ws[WS_MU + c];
        v = (vs + atot * mu_c) * invN;
    }
    float v2; TREE(v * v, v2);
    float nv = sqrtf(fmaxf(v2, EPSV));
    float lam = 2.f / fmaxf(1.f - mm, EPSV);
    float arg = fminf(fmaxf(lam * nv * 0.5f, -MAXT), MAXT);
    float tt = fast_tanh(arg);
    float sec = tt * v / nv;
    float xy; TREE(mu_c * sec, xy);
    float s2n; TREE(sec * sec, s2n);
    float A = 1.f + 2.f * xy + s2n;
    float B = 1.f - mm;
    float den = fmaxf(1.f + 2.f * xy + mm * s2n, EPSV);
    float munew = (A * mu_c + B * sec) / den;
    float mm2; TREE(munew * munew, mm2);
    float df = munew - mu_c;
    float stepn2; TREE(df * df, stepn2);
    if (tid < 128) ws[WS_MU + tid] = munew;
    if (tid == 0) {
        ws[WS_SC + S_MM] = mm2;
        if (stepn2 < STEP_TOL2) ws[WS_SC + S_FLAG] = 1.f;
    }
#undef TREE
}

// variance partials: one float per block into alpha[]
__global__ __launch_bounds__(BT) void k_var(const float* __restrict__ x,
                                            const uint4* __restrict__ xb,
                                            const float* __restrict__ ws,
                                            float* __restrict__ alpha,
                                            const int N, const int rd16) {
    const int tid = threadIdx.x;
    const int lane = tid & 63;
    const int wv = tid >> 6;
    const int q4 = lane & 3;
    const int gid = blockIdx.x * (BT / 4) + (tid >> 2);
    const int gstride = gridDim.x * (BT / 4);
    const float mm = ws[WS_SC + S_MM];
    const float4* mu4 = (const float4*)(ws + WS_MU);
    float4 mur[8];
#pragma unroll
    for (int k = 0; k < 4; ++k) {
        int o = 4 * k + q4;
        mur[2 * k] = mu4[o * 2];
        mur[2 * k + 1] = mu4[o * 2 + 1];
    }
    float accv = 0.f;
    for (int row = gid; row < N; row += gstride) {
        float4 xv[8];
        if (rd16) {
            const uint4* xbr = xb + (size_t)row * 16;
#pragma unroll
            for (int k = 0; k < 4; ++k) {
                uint4 u = xbr[4 * k + q4];
                xv[2 * k].x = lo_bf16(u.x); xv[2 * k].y = hi_bf16(u.x);
                xv[2 * k].z = lo_bf16(u.y); xv[2 * k].w = hi_bf16(u.y);
                xv[2 * k + 1].x = lo_bf16(u.z); xv[2 * k + 1].y = hi_bf16(u.z);
                xv[2 * k + 1].z = lo_bf16(u.w); xv[2 * k + 1].w = hi_bf16(u.w);
            }
        } else {
            const float4* xr = (const float4*)(x + (size_t)row * 128);
#pragma unroll
            for (int k = 0; k < 4; ++k) {
                int o = 4 * k + q4;
                xv[2 * k] = xr[o * 2];
                xv[2 * k + 1] = xr[o * 2 + 1];
            }
        }
        float dp = 0.f, np = 0.f;
#pragma unroll
        for (int k = 0; k < 8; ++k) {
            dp += mur[k].x * xv[k].x + mur[k].y * xv[k].y + mur[k].z * xv[k].z + mur[k].w * xv[k].w;
            np += xv[k].x * xv[k].x + xv[k].y * xv[k].y + xv[k].z * xv[k].z + xv[k].w * xv[k].w;
        }
        float d = qsum4(dp);
        float X2 = qsum4(np);
        float A = 1.f - 2.f * d + X2;
        float B = 1.f - mm;
        float den = fmaxf(1.f - 2.f * d + mm * X2, EPSV);
        float iv = 1.f / den;
        float m2 = (A * A * mm - 2.f * A * B * d + B * B * X2) * iv * iv;
        float n = sqrtf(fmaxf(m2, EPSV));
        float dist = 2.f * fast_atanh(fminf(n, BALLC));
        accv += dist * dist;
    }
#pragma unroll
    for (int m = 4; m < 64; m <<= 1) accv += __shfl_xor(accv, m);
    __shared__ float ls[8];
    if (lane == 0) ls[wv] = accv;
    __syncthreads();
    if (tid == 0) {
        float a = 0.f;
#pragma unroll
        for (int i = 0; i < 8; ++i) a += ls[i];
        alpha[blockIdx.x] = a;
    }
}

// finalize variance; p = exp0(mean_param), q = -mobius_add(p,-mu), Gram scalars
__global__ __launch_bounds__(128) void k_prep(const float* __restrict__ mean_param,
                                              const float* __restrict__ var_param,
                                              const float* __restrict__ alpha,
                                              float* __restrict__ ws,
                                              const int nblk, const float invN) {
    __shared__ float lred[128];
    int t = threadIdx.x;
#define FTREE(val, outv)                                     \
    lred[t] = (val);                                         \
    __syncthreads();                                         \
    for (int off = 64; off >= 1; off >>= 1) {                \
        if (t < off) lred[t] += lred[t + off];               \
        __syncthreads();                                     \
    }                                                        \
    outv = lred[0];                                          \
    __syncthreads();

    float vs = 0.f;
    for (int b = t; b < nblk; b += 128) vs += alpha[b];
    float varsum; FTREE(vs, varsum);
    float input_var = varsum * invN;
    float mpv = mean_param[t];
    float mpn2; FTREE(mpv * mpv, mpn2);
    float pn = sqrtf(fmaxf(mpn2, EPSV));
    float p_c = fast_tanh(pn) * mpv / pn;
    float pp; FTREE(p_c * p_c, pp);
    float mu_c = ws[WS_MU + t];
    float mm = ws[WS_SC + S_MM];
    float pm; FTREE(p_c * mu_c, pm);
    float A = 1.f - 2.f * pm + mm;
    float B = 1.f - pp;
    float den = fmaxf(1.f - 2.f * pm + pp * mm, EPSV);
    float q_c = (B * mu_c - A * p_c) / den;
    float qq; FTREE(q_c * q_c, qq);
    float mq; FTREE(mu_c * q_c, mq);
    float pq; FTREE(p_c * q_c, pq);
    float tfm = fmaxf(1.f - mm, EPSV);
    float tfp = fmaxf(1.f - pp, EPSV);
    float lam_p = 2.f / tfp;
    float svar = sqrtf(var_param[0] / (input_var + 1e-6f));
    float ks = (tfp / tfm) * svar;
    ws[WS_P + t] = p_c;
    ws[WS_Q + t] = q_c;
    if (t == 0) {
        ws[WS_SC + S_PP] = pp; ws[WS_SC + S_QQ] = qq; ws[WS_SC + S_MP] = pm;
        ws[WS_SC + S_MQ] = mq; ws[WS_SC + S_PQ] = pq; ws[WS_SC + S_TFM] = tfm;
        ws[WS_SC + S_LAMP] = lam_p; ws[WS_SC + S_KS] = ks;
    }
#undef FTREE
}

// final pass: out_i = expmap(p, ks * gyr(p,-mu, logmap(mu,x_i)))
__global__ __launch_bounds__(BT) void k_out(const float* __restrict__ x,
                                            float* __restrict__ out,
                                            const float* __restrict__ ws,
                                            const int N) {
    const float mm = ws[WS_SC + S_MM], pp = ws[WS_SC + S_PP], qq = ws[WS_SC + S_QQ];
    const float smp = ws[WS_SC + S_MP], smq = ws[WS_SC + S_MQ], spq = ws[WS_SC + S_PQ];
    const float tfm = ws[WS_SC + S_TFM], lam_p = ws[WS_SC + S_LAMP], ks = ws[WS_SC + S_KS];
    const int tid = threadIdx.x;
    const int lane = tid & 63;
    const int q4 = lane & 3;
    const int gid = blockIdx.x * (BT / 4) + (tid >> 2);
    const int gstride = gridDim.x * (BT / 4);
    const float4* mu4 = (const float4*)(ws + WS_MU);
    const float4* p4 = (const float4*)(ws + WS_P);
    const float4* qv4 = (const float4*)(ws + WS_Q);
    float4 mur[8], pr[8], qr[8];
#pragma unroll
    for (int k = 0; k < 4; ++k) {
        int o = 4 * k + q4;
        mur[2 * k] = mu4[o * 2];   mur[2 * k + 1] = mu4[o * 2 + 1];
        pr[2 * k] = p4[o * 2];     pr[2 * k + 1] = p4[o * 2 + 1];
        qr[2 * k] = qv4[o * 2];    qr[2 * k + 1] = qv4[o * 2 + 1];
    }
    for (int row = gid; row < N; row += gstride) {
        const float4* xr = (const float4*)(x + (size_t)row * 128);
        float4 xv[8];
#pragma unroll
        for (int k = 0; k < 4; ++k) {
            int o = 4 * k + q4;
            xv[2 * k] = xr[o * 2];
            xv[2 * k + 1] = xr[o * 2 + 1];
        }
        float am = 0.f, ap = 0.f, aq = 0.f, an = 0.f;
#pragma unroll
        for (int k = 0; k < 8; ++k) {
            am += mur[k].x * xv[k].x + mur[k].y * xv[k].y + mur[k].z * xv[k].z + mur[k].w * xv[k].w;
            ap += pr[k].x * xv[k].x + pr[k].y * xv[k].y + pr[k].z * xv[k].z + pr[k].w * xv[k].w;
            aq += qr[k].x * xv[k].x + qr[k].y * xv[k].y + qr[k].z * xv[k].z + qr[k].w * xv[k].w;
            an += xv[k].x * xv[k].x + xv[k].y * xv[k].y + xv[k].z * xv[k].z + xv[k].w * xv[k].w;
        }
        float Dm = qsum4(am), Dp = qsum4(ap), Dq = qsum4(aq), X2 = qsum4(an);

        float A = 1.f - 2.f * Dm + X2;
        float B = 1.f - mm;
        float den = fmaxf(1.f - 2.f * Dm + mm * X2, EPSV);
        float iv = 1.f / den;
        float m_cm = -A * iv, m_cx = B * iv;
        float m_dm = (-A * mm + B * Dm) * iv;
        float m_dp = (-A * smp + B * Dp) * iv;
        float m_dq = (-A * smq + B * Dq) * iv;
        float m_n2 = (A * A * mm - 2.f * A * B * Dm + B * B * X2) * iv * iv;

        float n1 = sqrtf(fmaxf(m_n2, EPSV));
        float s1 = tfm * fast_atanh(fminf(n1, BALLC)) / n1;
        float t_cm = s1 * m_cm, t_cx = s1 * m_cx;
        float t_dm = s1 * m_dm, t_dp = s1 * m_dp, t_dq = s1 * m_dq;
        float t_n2 = s1 * s1 * m_n2;

        float xy = -t_dm, y2 = t_n2;
        A = 1.f + 2.f * xy + y2;
        B = 1.f - mm;
        den = fmaxf(1.f + 2.f * xy + mm * y2, EPSV);
        iv = 1.f / den;
        float w_cm = (-A + B * t_cm) * iv;
        float w_cx = B * t_cx * iv;
        float w_dp = (-A * smp + B * t_dp) * iv;
        float w_dq = (-A * smq + B * t_dq) * iv;
        float w_n2 = (A * A * mm + 2.f * A * B * xy + B * B * y2) * iv * iv;

        xy = w_dp; y2 = w_n2;
        A = 1.f + 2.f * xy + y2;
        B = 1.f - pp;
        den = fmaxf(1.f + 2.f * xy + pp * y2, EPSV);
        iv = 1.f / den;
        float w2_cm = B * w_cm * iv;
        float w2_cp = A * iv;
        float w2_cx = B * w_cx * iv;
        float w2_dp = (A * pp + B * w_dp) * iv;
        float w2_dq = (A * spq + B * w_dq) * iv;
        float w2_n2 = (A * A * pp + 2.f * A * B * xy + B * B * y2) * iv * iv;

        xy = w2_dq; y2 = w2_n2;
        A = 1.f + 2.f * xy + y2;
        B = 1.f - qq;
        den = fmaxf(1.f + 2.f * xy + qq * y2, EPSV);
        iv = 1.f / den;
        float w3_cm = B * w2_cm * iv;
        float w3_cp = B * w2_cp * iv;
        float w3_cq = A * iv;
        float w3_cx = B * w2_cx * iv;
        float w3_dp = (A * spq + B * w2_dp) * iv;
        float w3_n2 = (A * A * qq + 2.f * A * B * xy + B * B * y2) * iv * iv;

        float u_n2 = ks * ks * w3_n2;
        float nu = sqrtf(fmaxf(u_n2, EPSV));
        float arg = fminf(fmaxf(lam_p * nu * 0.5f, -MAXT), MAXT);
        float sf = fast_tanh(arg) * ks / nu;
        float s_cm = sf * w3_cm, s_cp = sf * w3_cp, s_cq = sf * w3_cq, s_cx = sf * w3_cx;
        float s_dp = sf * w3_dp;
        float s_n2 = sf * sf * w3_n2;

        xy = s_dp; y2 = s_n2;
        A = 1.f + 2.f * xy + y2;
        B = 1.f - pp;
        den = fmaxf(1.f + 2.f * xy + pp * y2, EPSV);
        iv = 1.f / den;
        float o_cm = B * s_cm * iv;
        float o_cp = (A + B * s_cp) * iv;
        float o_cq = B * s_cq * iv;
        float o_cx = B * s_cx * iv;

        float4* orow = (float4*)(out + (size_t)row * 128);
#pragma unroll
        for (int k = 0; k < 4; ++k) {
            int o = 4 * k + q4;
#pragma unroll
            for (int h = 0; h < 2; ++h) {
                float4 xvk = xv[2 * k + h];
                float4 mk = mur[2 * k + h], pk = pr[2 * k + h], qk = qr[2 * k + h];
                float4 ov;
                ov.x = o_cm * mk.x + o_cp * pk.x + o_cq * qk.x + o_cx * xvk.x;
                ov.y = o_cm * mk.y + o_cp * pk.y + o_cq * qk.y + o_cx * xvk.y;
                ov.z = o_cm * mk.z + o_cp * pk.z + o_cq * qk.z + o_cx * xvk.z;
                ov.w = o_cm * mk.w + o_cp * pk.w + o_cq * qk.w + o_cx * xvk.w;
                orow[o * 2 + h] = ov;
            }
        }
    }
}

extern "C" void kernel_launch(void* const* d_in, const int* in_sizes, int n_in,
                              void* d_out, int out_size, void* d_ws, size_t ws_size,
                              hipStream_t stream) {
    const float* x = (const float*)d_in[0];
    const float* mpar = (const float*)d_in[1];
    const float* vpar = (const float*)d_in[2];
    float* out = (float*)d_out;
    float* ws = (float*)d_ws;
    int N = in_sizes[0] / 128;
    float invN = 1.f / (float)N;

    long wsf = (long)(ws_size / sizeof(float));
    int nb0 = NB0, nb1 = NB1;
    {
        long nb = (wsf - WS_HDR) / 133;   // part(132) + alpha(1) per block
        if (nb < nb0) nb0 = (nb < 8) ? 8 : (int)nb;
        if (nb1 > nb0) nb1 = nb0;
    }
    float* part = ws + WS_HDR;
    float* alpha = part + (long)nb0 * 132;
    long off_xb = WS_HDR + (long)nb0 * 133;
    off_xb = (off_xb + 3) & ~3L;  // 16B align
    uint4* xb = (uint4*)(ws + off_xb);
    int use16 = (ws_size >= (size_t)off_xb * sizeof(float) + (size_t)N * 256) ? 1 : 0;

    hipLaunchKernelGGL(k_zero, dim3(1), dim3(256), 0, stream, ws);
    // pass 0 (mu = 0, equals exp0(mean(log0 x)) init); converts x -> bf16 if room
    hipLaunchKernelGGL(k_pass, dim3(nb0), dim3(BT), 0, stream,
                       x, xb, ws, part, alpha, N, use16 ? 1 : 3);
    hipLaunchKernelGGL(k_upd, dim3(1), dim3(1024), 0, stream, ws, part, alpha, nb0, invN, 1);
    for (int it = 1; it < 16; ++it) {
        hipLaunchKernelGGL(k_pass, dim3(nb1), dim3(BT), 0, stream,
                           x, xb, ws, part, alpha, N, use16 ? 2 : 0);
        hipLaunchKernelGGL(k_upd, dim3(1), dim3(1024), 0, stream, ws, part, alpha, nb1, invN, 0);
    }
    hipLaunchKernelGGL(k_var, dim3(nb1), dim3(BT), 0, stream, x, xb, ws, alpha, N, use16);
    hipLaunchKernelGGL(k_prep, dim3(1), dim3(128), 0, stream, mpar, vpar, alpha, ws, nb1, invN);
    hipLaunchKernelGGL(k_out, dim3(nb0), dim3(BT), 0, stream, x, out, ws, N);
}

// Round 6
// 472.170 us; speedup vs baseline: 2.5532x; 1.1066x over previous
//
#include <hip/hip_runtime.h>
#include <math.h>

#define EPSV 1e-12f
#define BALLC (1.0f - 1e-6f)
#define MAXT 15.0f
#define NBP 256      // pass grid (blocks)
#define BTP 1024     // pass block threads
#define NBO 512      // k_out grid
#define BTO 512      // k_out block threads
#define STEP_TOL2 1e-8f

// ws float offsets
#define SLOT0 0      // {mu[128], mm, flag}
#define SLOT1 160
#define MUF 320
#define PF 448
#define QF 576
#define SCF 704      // 16 scalars
#define PART 768     // NBP * 132 (128 vec + alpha + pad)
#define ALPHA2 (PART + NBP * 132)
#define XBOFF (ALPHA2 + NBP)   // = 34816, 16B-aligned
#define C_MM 0
#define C_PP 1
#define C_QQ 2
#define C_MP 3
#define C_MQ 4
#define C_PQ 5
#define C_TFM 6
#define C_LAMP 7
#define C_KS 8

__device__ __forceinline__ float fast_atanh(float x) {
    return 0.5f * __logf((1.f + x) / (1.f - x));
}
__device__ __forceinline__ float fast_tanh(float x) {
    float e = __expf(-2.f * x);
    return (1.f - e) / (1.f + e);
}
__device__ __forceinline__ float qsum8(float v) {
    v += __shfl_xor(v, 1);
    v += __shfl_xor(v, 2);
    v += __shfl_xor(v, 4);
    return v;
}
__device__ __forceinline__ unsigned pack2_bf16(float a, float b) {
    unsigned ua = __float_as_uint(a), ub = __float_as_uint(b);
    ua += 0x7FFFu + ((ua >> 16) & 1u);
    ub += 0x7FFFu + ((ub >> 16) & 1u);
    return (ua >> 16) | (ub & 0xFFFF0000u);
}
__device__ __forceinline__ float lo_bf16(unsigned u) { return __uint_as_float(u << 16); }
__device__ __forceinline__ float hi_bf16(unsigned u) { return __uint_as_float(u & 0xFFFF0000u); }

// all threads execute; broadcasts lred[0]
#define TREE(val, outv)                                      \
    if (tid < 128) lred[tid] = (val);                        \
    __syncthreads();                                         \
    for (int off = 64; off >= 1; off >>= 1) {                \
        if (tid < off) lred[tid] += lred[tid + off];         \
        __syncthreads();                                     \
    }                                                        \
    outv = lred[0];                                          \
    __syncthreads();

__global__ void k_zero(float* ws) {
    if (threadIdx.x == 0) {
        ws[SLOT0 + 128] = 0.f; ws[SLOT0 + 129] = 0.f;
        ws[SLOT1 + 128] = 0.f; ws[SLOT1 + 129] = 0.f;
    }
}

// Reduce partials + expmap update: mu_new = expmap(mu_old, mean tangent).
// All threads participate (barriers). Result: lmu[0..127], *p_mm, *p_conv.
__device__ __forceinline__ void reduce_update(
        const float* __restrict__ part, const int nblk, const float invN,
        const float* __restrict__ muold, const float mmold,
        float* lmu, float (*lvec)[128], float* lred,
        float* p_mm, int* p_conv, const int tid) {
    {
        int c = tid & 127, sg = tid >> 7;
        float s = 0.f;
        for (int b = sg; b < nblk; b += 8) s += part[(size_t)b * 132 + c];
        lvec[sg][c] = s;
    }
    float av = 0.f;
    if (tid < 128)
        for (int b = tid; b < nblk; b += 128) av += part[(size_t)b * 132 + 128];
    __syncthreads();
    float atot; TREE(av, atot);
    float mu_c = 0.f, v = 0.f;
    if (tid < 128) {
        float vs = 0.f;
#pragma unroll
        for (int i = 0; i < 8; ++i) vs += lvec[i][tid];
        mu_c = muold ? muold[tid] : 0.f;
        v = (vs + atot * mu_c) * invN;
    }
    float v2; TREE(v * v, v2);
    float nv = sqrtf(fmaxf(v2, EPSV));
    float lam = 2.f / fmaxf(1.f - mmold, EPSV);
    float arg = fminf(lam * nv * 0.5f, MAXT);
    float tt = fast_tanh(arg);
    float sec = tt * v / nv;
    float xy; TREE(mu_c * sec, xy);
    float s2n; TREE(sec * sec, s2n);
    float A = 1.f + 2.f * xy + s2n;
    float B = 1.f - mmold;
    float den = fmaxf(1.f + 2.f * xy + mmold * s2n, EPSV);
    float munew = (A * mu_c + B * sec) / den;
    float mm2; TREE(munew * munew, mm2);
    float df = munew - mu_c;
    float st2; TREE(df * df, st2);
    if (tid < 128) lmu[tid] = munew;
    *p_mm = mm2;
    *p_conv = (st2 < STEP_TOL2) ? 1 : 0;
    __syncthreads();
}

// ---------------------------------------------------------------------------
// Pass j (j = 0..15).
//   j==0 : mu = 0 (init pass), fp32 read (+bf16 store if use16), no prologue.
//   j>=1 : prologue reduces partials_{j-1} -> mu_{j-1} (redundant per block,
//          deterministic); block 0 publishes to slot j&1. Main loop over x
//          (bf16 if use16). j==15 additionally accumulates dist^2 (variance).
//   Early-out: if slot flag set, copy mu forward; skip main loop (j!=15).
// ---------------------------------------------------------------------------
__global__ __launch_bounds__(BTP) void k_pass(
        const float* __restrict__ x, uint2* __restrict__ xb,
        float* __restrict__ ws, float* __restrict__ part,
        float* __restrict__ alpha2, const int N, const float invN,
        const int j, const int use16) {
    __shared__ float lvec[16][128];
    __shared__ float lred[128];
    __shared__ float lmu[128];
    __shared__ float lalpha[16];
    __shared__ float lv2[16];
    const int tid = threadIdx.x;
    const int lane = tid & 63;
    const int wv = tid >> 6;     // 0..15
    const int sub = lane & 7;
    const int gid = blockIdx.x * (BTP / 8) + (tid >> 3);
    const int gstride = gridDim.x * (BTP / 8);

    float mm = 0.f, tfm = 1.f;
    bool frozen = false;
    if (j > 0) {
        const float* slot_in = ws + (((j - 1) & 1) ? SLOT1 : SLOT0);
        float* slot_out = ws + ((j & 1) ? SLOT1 : SLOT0);
        float flag = slot_in[129];
        frozen = (flag != 0.f);
        float mmn;
        int conv = 1;
        if (frozen) {
            if (tid < 128) lmu[tid] = slot_in[tid];
            mmn = slot_in[128];
            __syncthreads();
        } else {
            float mmold = (j == 1) ? 0.f : slot_in[128];
            reduce_update(part, gridDim.x, invN,
                          (j == 1) ? (const float*)nullptr : slot_in, mmold,
                          lmu, (float(*)[128])lvec, lred, &mmn, &conv, tid);
        }
        if (blockIdx.x == 0) {
            if (tid < 128) slot_out[tid] = lmu[tid];
            if (tid == 0) { slot_out[128] = mmn; slot_out[129] = conv ? 1.f : 0.f; }
        }
        mm = mmn;
        tfm = fmaxf(1.f - mm, EPSV);
        if (frozen && j != 15) return;  // nothing new to compute
    }

    const bool first = (j == 0);
    const bool dovar = (j == 15);
    float4 mur[4];
    if (j > 0) {
        const float4* lmu4 = (const float4*)lmu;
#pragma unroll
        for (int k = 0; k < 4; ++k) mur[k] = lmu4[k * 8 + sub];
    } else {
#pragma unroll
        for (int k = 0; k < 4; ++k) mur[k] = make_float4(0.f, 0.f, 0.f, 0.f);
    }
    float4 acc[4];
#pragma unroll
    for (int k = 0; k < 4; ++k) acc[k] = make_float4(0.f, 0.f, 0.f, 0.f);
    float accA = 0.f, accV = 0.f;

    for (int row = gid; row < N; row += gstride) {
        float4 xv[4];
        if (!first && use16) {
            const uint2* xbr = xb + (size_t)row * 32;
#pragma unroll
            for (int k = 0; k < 4; ++k) {
                uint2 u = xbr[k * 8 + sub];
                xv[k].x = lo_bf16(u.x); xv[k].y = hi_bf16(u.x);
                xv[k].z = lo_bf16(u.y); xv[k].w = hi_bf16(u.y);
            }
        } else {
            const float4* xr = (const float4*)(x + (size_t)row * 128);
#pragma unroll
            for (int k = 0; k < 4; ++k) xv[k] = xr[k * 8 + sub];
            if (first && use16) {
                uint2* xbr = xb + (size_t)row * 32;
#pragma unroll
                for (int k = 0; k < 4; ++k) {
                    uint2 u;
                    u.x = pack2_bf16(xv[k].x, xv[k].y);
                    u.y = pack2_bf16(xv[k].z, xv[k].w);
                    xbr[k * 8 + sub] = u;
                }
            }
        }
        float dp = 0.f, np = 0.f;
#pragma unroll
        for (int k = 0; k < 4; ++k) {
            dp += mur[k].x * xv[k].x + mur[k].y * xv[k].y + mur[k].z * xv[k].z + mur[k].w * xv[k].w;
            np += xv[k].x * xv[k].x + xv[k].y * xv[k].y + xv[k].z * xv[k].z + xv[k].w * xv[k].w;
        }
        float d = first ? 0.f : qsum8(dp);
        float X2 = qsum8(np);
        // m = mobius_add(-mu, x) = (-A*mu + B*x)/den
        float A = 1.f - 2.f * d + X2;
        float B = 1.f - mm;
        float den = fmaxf(1.f - 2.f * d + mm * X2, EPSV);
        float iv = 1.f / den;
        float m2 = (A * A * mm - 2.f * A * B * d + B * B * X2) * iv * iv;
        float n = sqrtf(fmaxf(m2, EPSV));
        float at = fast_atanh(fminf(n, BALLC));
        float s = tfm * at / n;
        accA += s * (-A * iv);
        float delta = s * (B * iv);
        if (dovar) accV += 4.f * at * at;  // dist^2 = (2 atanh n)^2
#pragma unroll
        for (int k = 0; k < 4; ++k) {
            acc[k].x += delta * xv[k].x;
            acc[k].y += delta * xv[k].y;
            acc[k].z += delta * xv[k].z;
            acc[k].w += delta * xv[k].w;
        }
    }

    // sum across the 8 groups of each wave (xor bits 3..5); per-group copies
    // of accA/accV are identical across sub lanes so no overcount.
#pragma unroll
    for (int m = 8; m < 64; m <<= 1) {
#pragma unroll
        for (int k = 0; k < 4; ++k) {
            acc[k].x += __shfl_xor(acc[k].x, m);
            acc[k].y += __shfl_xor(acc[k].y, m);
            acc[k].z += __shfl_xor(acc[k].z, m);
            acc[k].w += __shfl_xor(acc[k].w, m);
        }
        accA += __shfl_xor(accA, m);
        if (dovar) accV += __shfl_xor(accV, m);
    }
    if (lane < 8) {
#pragma unroll
        for (int k = 0; k < 4; ++k) {
            int c = (k * 8 + lane) * 4;
            lvec[wv][c + 0] = acc[k].x;
            lvec[wv][c + 1] = acc[k].y;
            lvec[wv][c + 2] = acc[k].z;
            lvec[wv][c + 3] = acc[k].w;
        }
    }
    if (lane == 0) { lalpha[wv] = accA; lv2[wv] = accV; }
    __syncthreads();
    if (tid < 128) {
        float s = 0.f;
#pragma unroll
        for (int i = 0; i < 16; ++i) s += lvec[i][tid];
        part[(size_t)blockIdx.x * 132 + tid] = s;
    }
    if (tid == 0) {
        float a = 0.f, v2s = 0.f;
#pragma unroll
        for (int i = 0; i < 16; ++i) { a += lalpha[i]; v2s += lv2[i]; }
        part[(size_t)blockIdx.x * 132 + 128] = a;
        if (dovar) alpha2[blockIdx.x] = v2s;
    }
}

// final mu update + variance finalize + p/q/Gram prep (1 block)
__global__ __launch_bounds__(1024) void k_fin(
        const float* __restrict__ mpar, const float* __restrict__ vpar,
        float* __restrict__ ws, const float* __restrict__ part,
        const float* __restrict__ alpha2, const int nblk, const float invN) {
    __shared__ float lvec[8][128];
    __shared__ float lred[128];
    __shared__ float lmu[128];
    const int tid = threadIdx.x;
    const float* slot_in = ws + SLOT1;  // pass 15 wrote M_14 here (15&1 == 1)
    float flag = slot_in[129];
    float mm;
    int conv = 1;
    if (flag != 0.f) {
        if (tid < 128) lmu[tid] = slot_in[tid];
        mm = slot_in[128];
        __syncthreads();
    } else {
        reduce_update(part, nblk, invN, slot_in, slot_in[128],
                      lmu, lvec, lred, &mm, &conv, tid);
    }
    float av = 0.f;
    if (tid < 128)
        for (int b = tid; b < nblk; b += 128) av += alpha2[b];
    float varsum; TREE(av, varsum);
    float input_var = varsum * invN;
    float mpv = (tid < 128) ? mpar[tid] : 0.f;
    float mpn2; TREE(mpv * mpv, mpn2);
    float pn = sqrtf(fmaxf(mpn2, EPSV));
    float p_c = fast_tanh(pn) * mpv / pn;
    float pp; TREE(p_c * p_c, pp);
    float mu_c = (tid < 128) ? lmu[tid] : 0.f;
    float pm; TREE(p_c * mu_c, pm);
    float A = 1.f - 2.f * pm + mm;
    float B = 1.f - pp;
    float den = fmaxf(1.f - 2.f * pm + pp * mm, EPSV);
    float q_c = (B * mu_c - A * p_c) / den;
    float qq; TREE(q_c * q_c, qq);
    float mq; TREE(mu_c * q_c, mq);
    float pq; TREE(p_c * q_c, pq);
    float tfm = fmaxf(1.f - mm, EPSV);
    float tfp = fmaxf(1.f - pp, EPSV);
    float lam_p = 2.f / tfp;
    float svar = sqrtf(vpar[0] / (input_var + 1e-6f));
    float ks = (tfp / tfm) * svar;
    if (tid < 128) {
        ws[MUF + tid] = lmu[tid];
        ws[PF + tid] = p_c;
        ws[QF + tid] = q_c;
    }
    if (tid == 0) {
        float* sc = ws + SCF;
        sc[C_MM] = mm; sc[C_PP] = pp; sc[C_QQ] = qq; sc[C_MP] = pm;
        sc[C_MQ] = mq; sc[C_PQ] = pq; sc[C_TFM] = tfm; sc[C_LAMP] = lam_p;
        sc[C_KS] = ks;
    }
}

// out_i = expmap(p, ks * gyr(p,-mu, logmap(mu,x_i))); span{mu,p,q,x} closed form
__global__ __launch_bounds__(BTO) void k_out(const float* __restrict__ x,
                                             float* __restrict__ out,
                                             const float* __restrict__ ws,
                                             const int N) {
    const float* sc = ws + SCF;
    const float mm = sc[C_MM], pp = sc[C_PP], qq = sc[C_QQ];
    const float smp = sc[C_MP], smq = sc[C_MQ], spq = sc[C_PQ];
    const float tfm = sc[C_TFM], lam_p = sc[C_LAMP], ks = sc[C_KS];
    const int tid = threadIdx.x;
    const int lane = tid & 63;
    const int sub = lane & 7;
    const int gid = blockIdx.x * (BTO / 8) + (tid >> 3);
    const int gstride = gridDim.x * (BTO / 8);
    const float4* mu4 = (const float4*)(ws + MUF);
    const float4* p4 = (const float4*)(ws + PF);
    const float4* qv4 = (const float4*)(ws + QF);
    float4 mur[4], pr[4], qr[4];
#pragma unroll
    for (int k = 0; k < 4; ++k) {
        mur[k] = mu4[k * 8 + sub];
        pr[k] = p4[k * 8 + sub];
        qr[k] = qv4[k * 8 + sub];
    }
    for (int row = gid; row < N; row += gstride) {
        const float4* xr = (const float4*)(x + (size_t)row * 128);
        float4 xv[4];
#pragma unroll
        for (int k = 0; k < 4; ++k) xv[k] = xr[k * 8 + sub];
        float am = 0.f, ap = 0.f, aq = 0.f, an = 0.f;
#pragma unroll
        for (int k = 0; k < 4; ++k) {
            am += mur[k].x * xv[k].x + mur[k].y * xv[k].y + mur[k].z * xv[k].z + mur[k].w * xv[k].w;
            ap += pr[k].x * xv[k].x + pr[k].y * xv[k].y + pr[k].z * xv[k].z + pr[k].w * xv[k].w;
            aq += qr[k].x * xv[k].x + qr[k].y * xv[k].y + qr[k].z * xv[k].z + qr[k].w * xv[k].w;
            an += xv[k].x * xv[k].x + xv[k].y * xv[k].y + xv[k].z * xv[k].z + xv[k].w * xv[k].w;
        }
        float Dm = qsum8(am), Dp = qsum8(ap), Dq = qsum8(aq), X2 = qsum8(an);

        float A = 1.f - 2.f * Dm + X2;
        float B = 1.f - mm;
        float den = fmaxf(1.f - 2.f * Dm + mm * X2, EPSV);
        float iv = 1.f / den;
        float m_cm = -A * iv, m_cx = B * iv;
        float m_dm = (-A * mm + B * Dm) * iv;
        float m_dp = (-A * smp + B * Dp) * iv;
        float m_dq = (-A * smq + B * Dq) * iv;
        float m_n2 = (A * A * mm - 2.f * A * B * Dm + B * B * X2) * iv * iv;

        float n1 = sqrtf(fmaxf(m_n2, EPSV));
        float s1 = tfm * fast_atanh(fminf(n1, BALLC)) / n1;
        float t_cm = s1 * m_cm, t_cx = s1 * m_cx;
        float t_dm = s1 * m_dm, t_dp = s1 * m_dp, t_dq = s1 * m_dq;
        float t_n2 = s1 * s1 * m_n2;

        float xy = -t_dm, y2 = t_n2;
        A = 1.f + 2.f * xy + y2;
        B = 1.f - mm;
        den = fmaxf(1.f + 2.f * xy + mm * y2, EPSV);
        iv = 1.f / den;
        float w_cm = (-A + B * t_cm) * iv;
        float w_cx = B * t_cx * iv;
        float w_dp = (-A * smp + B * t_dp) * iv;
        float w_dq = (-A * smq + B * t_dq) * iv;
        float w_n2 = (A * A * mm + 2.f * A * B * xy + B * B * y2) * iv * iv;

        xy = w_dp; y2 = w_n2;
        A = 1.f + 2.f * xy + y2;
        B = 1.f - pp;
        den = fmaxf(1.f + 2.f * xy + pp * y2, EPSV);
        iv = 1.f / den;
        float w2_cm = B * w_cm * iv;
        float w2_cp = A * iv;
        float w2_cx = B * w_cx * iv;
        float w2_dp = (A * pp + B * w_dp) * iv;
        float w2_dq = (A * spq + B * w_dq) * iv;
        float w2_n2 = (A * A * pp + 2.f * A * B * xy + B * B * y2) * iv * iv;

        xy = w2_dq; y2 = w2_n2;
        A = 1.f + 2.f * xy + y2;
        B = 1.f - qq;
        den = fmaxf(1.f + 2.f * xy + qq * y2, EPSV);
        iv = 1.f / den;
        float w3_cm = B * w2_cm * iv;
        float w3_cp = B * w2_cp * iv;
        float w3_cq = A * iv;
        float w3_cx = B * w2_cx * iv;
        float w3_dp = (A * spq + B * w2_dp) * iv;
        float w3_n2 = (A * A * qq + 2.f * A * B * xy + B * B * y2) * iv * iv;

        float u_n2 = ks * ks * w3_n2;
        float nu = sqrtf(fmaxf(u_n2, EPSV));
        float arg = fminf(fmaxf(lam_p * nu * 0.5f, -MAXT), MAXT);
        float sf = fast_tanh(arg) * ks / nu;
        float s_cm = sf * w3_cm, s_cp = sf * w3_cp, s_cq = sf * w3_cq, s_cx = sf * w3_cx;
        float s_dp = sf * w3_dp;
        float s_n2 = sf * sf * w3_n2;

        xy = s_dp; y2 = s_n2;
        A = 1.f + 2.f * xy + y2;
        B = 1.f - pp;
        den = fmaxf(1.f + 2.f * xy + pp * y2, EPSV);
        iv = 1.f / den;
        float o_cm = B * s_cm * iv;
        float o_cp = (A + B * s_cp) * iv;
        float o_cq = B * s_cq * iv;
        float o_cx = B * s_cx * iv;

        float4* orow = (float4*)(out + (size_t)row * 128);
#pragma unroll
        for (int k = 0; k < 4; ++k) {
            float4 mk = mur[k], pk = pr[k], qk = qr[k], xk = xv[k];
            float4 ov;
            ov.x = o_cm * mk.x + o_cp * pk.x + o_cq * qk.x + o_cx * xk.x;
            ov.y = o_cm * mk.y + o_cp * pk.y + o_cq * qk.y + o_cx * xk.y;
            ov.z = o_cm * mk.z + o_cp * pk.z + o_cq * qk.z + o_cx * xk.z;
            ov.w = o_cm * mk.w + o_cp * pk.w + o_cq * qk.w + o_cx * xk.w;
            orow[k * 8 + sub] = ov;
        }
    }
}

extern "C" void kernel_launch(void* const* d_in, const int* in_sizes, int n_in,
                              void* d_out, int out_size, void* d_ws, size_t ws_size,
                              hipStream_t stream) {
    const float* x = (const float*)d_in[0];
    const float* mpar = (const float*)d_in[1];
    const float* vpar = (const float*)d_in[2];
    float* out = (float*)d_out;
    float* ws = (float*)d_ws;
    int N = in_sizes[0] / 128;
    float invN = 1.f / (float)N;

    long wsf = (long)(ws_size / sizeof(float));
    float* part = ws + PART;
    float* alpha2 = ws + ALPHA2;
    uint2* xb = (uint2*)(ws + XBOFF);
    int use16 = (wsf >= (long)XBOFF + (long)N * 64) ? 1 : 0;

    hipLaunchKernelGGL(k_zero, dim3(1), dim3(64), 0, stream, ws);
    for (int j = 0; j < 16; ++j)
        hipLaunchKernelGGL(k_pass, dim3(NBP), dim3(BTP), 0, stream,
                           x, xb, ws, part, alpha2, N, invN, j, use16);
    hipLaunchKernelGGL(k_fin, dim3(1), dim3(1024), 0, stream,
                       mpar, vpar, ws, part, alpha2, NBP, invN);
    hipLaunchKernelGGL(k_out, dim3(NBO), dim3(BTO), 0, stream, x, out, ws, N);
}

// Round 7
// 434.429 us; speedup vs baseline: 2.7750x; 1.0869x over previous
//
#include <hip/hip_runtime.h>
#include <math.h>

#define EPSV 1e-12f
#define BALLC (1.0f - 1e-6f)
#define MAXT 15.0f
#define NBP 256      // pass grid (blocks)
#define BTP 1024     // pass block threads
#define NBO 512      // k_out grid
#define BTO 512      // k_out block threads
#define STEP_TOL2 1e-8f

// ws float offsets
#define SLOT0 0      // {mu[128], mm, flag}
#define SLOT1 160
#define MUF 320
#define PF 448
#define QF 576
#define SCF 704      // 16 scalars
#define PART 768     // NBP * 132 (128 vec + alpha + pad)
#define ALPHA2 (PART + NBP * 132)
#define XBOFF (ALPHA2 + NBP)   // 16B-aligned
#define C_MM 0
#define C_PP 1
#define C_QQ 2
#define C_MP 3
#define C_MQ 4
#define C_PQ 5
#define C_TFM 6
#define C_LAMP 7
#define C_KS 8

__device__ __forceinline__ float fast_atanh(float x) {
    return 0.5f * __logf((1.f + x) / (1.f - x));
}
__device__ __forceinline__ float fast_tanh(float x) {
    float e = __expf(-2.f * x);
    return (1.f - e) / (1.f + e);
}
__device__ __forceinline__ float qsum8(float v) {
    v += __shfl_xor(v, 1);
    v += __shfl_xor(v, 2);
    v += __shfl_xor(v, 4);
    return v;
}
__device__ __forceinline__ float wsum64(float v) {
    v += __shfl_xor(v, 1);
    v += __shfl_xor(v, 2);
    v += __shfl_xor(v, 4);
    v += __shfl_xor(v, 8);
    v += __shfl_xor(v, 16);
    v += __shfl_xor(v, 32);
    return v;
}
__device__ __forceinline__ unsigned pack2_bf16(float a, float b) {
    unsigned ua = __float_as_uint(a), ub = __float_as_uint(b);
    ua += 0x7FFFu + ((ua >> 16) & 1u);
    ub += 0x7FFFu + ((ub >> 16) & 1u);
    return (ua >> 16) | (ub & 0xFFFF0000u);
}
__device__ __forceinline__ float lo_bf16(unsigned u) { return __uint_as_float(u << 16); }
__device__ __forceinline__ float hi_bf16(unsigned u) { return __uint_as_float(u & 0xFFFF0000u); }

__global__ void k_zero(float* ws) {
    if (threadIdx.x == 0) {
        ws[SLOT0 + 128] = 0.f; ws[SLOT0 + 129] = 0.f;
        ws[SLOT1 + 128] = 0.f; ws[SLOT1 + 129] = 0.f;
    }
}

// ---------------------------------------------------------------------------
// mu <- expmap(mu_old, mean tangent), computed from per-block partials.
// All threads call (2 barriers). Wave 0 does the scalar math with shuffle
// butterflies (no LDS trees). Outputs: lmu[0..127], lscal[0]=||mu||^2,
// lscal[1]=conv flag. Deterministic: identical op order in every block.
// ---------------------------------------------------------------------------
__device__ __forceinline__ void mu_update_w0(
        const float* __restrict__ part, const int nblk, const float invN,
        const float* __restrict__ slot_in, const bool haveold,
        float (*lvec)[128], float* lmu, float* lscal, const int tid) {
    {
        int c = tid & 127, sg = tid >> 7;
        float s = 0.f;
        for (int b = sg; b < nblk; b += 8) s += part[(size_t)b * 132 + c];
        lvec[sg][c] = s;
    }
    __syncthreads();
    if (tid < 64) {
        float vs0 = 0.f, vs1 = 0.f;
#pragma unroll
        for (int i = 0; i < 8; ++i) { vs0 += lvec[i][tid]; vs1 += lvec[i][tid + 64]; }
        float a = 0.f;
        for (int b = tid; b < nblk; b += 64) a += part[(size_t)b * 132 + 128];
        float atot = wsum64(a);
        float mmold = haveold ? slot_in[128] : 0.f;
        float mu0 = haveold ? slot_in[tid] : 0.f;
        float mu1 = haveold ? slot_in[tid + 64] : 0.f;
        float v0 = (vs0 + atot * mu0) * invN;
        float v1 = (vs1 + atot * mu1) * invN;
        float v2 = wsum64(v0 * v0 + v1 * v1);
        float nv = sqrtf(fmaxf(v2, EPSV));
        float lam = 2.f / fmaxf(1.f - mmold, EPSV);
        float arg = fminf(lam * nv * 0.5f, MAXT);
        float tt = fast_tanh(arg);
        float sc = tt / nv;
        float sec0 = sc * v0, sec1 = sc * v1;
        float xy = wsum64(mu0 * sec0 + mu1 * sec1);
        float s2n = wsum64(sec0 * sec0 + sec1 * sec1);
        float A = 1.f + 2.f * xy + s2n;
        float B = 1.f - mmold;
        float den = fmaxf(1.f + 2.f * xy + mmold * s2n, EPSV);
        float idn = 1.f / den;
        float mun0 = (A * mu0 + B * sec0) * idn;
        float mun1 = (A * mu1 + B * sec1) * idn;
        float mm2 = wsum64(mun0 * mun0 + mun1 * mun1);
        float d0 = mun0 - mu0, d1 = mun1 - mu1;
        float st2 = wsum64(d0 * d0 + d1 * d1);
        lmu[tid] = mun0;
        lmu[tid + 64] = mun1;
        if (tid == 0) {
            lscal[0] = mm2;
            lscal[1] = (st2 < STEP_TOL2) ? 1.f : 0.f;
        }
    }
    __syncthreads();
}

// ---------------------------------------------------------------------------
// Pass j (j = 0..15).
//   j==0 : mu = 0 (init), fp32 read (+bf16 store if use16), no prologue.
//   j>=1 : prologue reduces partials_{j-1} -> mu_{j-1} (redundant per block,
//          deterministic); block 0 publishes to slot j&1. Main loop over x
//          (bf16 if use16). j==15 additionally accumulates dist^2 (variance).
//   Early-out: if slot flag set, copy mu forward; skip main loop (j!=15).
// ---------------------------------------------------------------------------
__global__ __launch_bounds__(BTP) void k_pass(
        const float* __restrict__ x, uint2* __restrict__ xb,
        float* __restrict__ ws, float* __restrict__ part,
        float* __restrict__ alpha2, const int N, const float invN,
        const int j, const int use16) {
    __shared__ float lvec[16][128];
    __shared__ __align__(16) float lmu[128];
    __shared__ float lscal[2];
    __shared__ float lalpha[16];
    __shared__ float lv2[16];
    const int tid = threadIdx.x;
    const int lane = tid & 63;
    const int wv = tid >> 6;     // 0..15
    const int sub = lane & 7;
    const int gid = blockIdx.x * (BTP / 8) + (tid >> 3);
    const int gstride = gridDim.x * (BTP / 8);

    float mm = 0.f, tfm = 1.f;
    bool frozen = false;
    if (j > 0) {
        const float* slot_in = ws + (((j - 1) & 1) ? SLOT1 : SLOT0);
        float* slot_out = ws + ((j & 1) ? SLOT1 : SLOT0);
        frozen = (slot_in[129] != 0.f);
        if (frozen) {
            if (tid < 128) lmu[tid] = slot_in[tid];
            if (tid == 0) { lscal[0] = slot_in[128]; lscal[1] = 1.f; }
            __syncthreads();
        } else {
            mu_update_w0(part, gridDim.x, invN, slot_in, j > 1,
                         lvec, lmu, lscal, tid);
        }
        mm = lscal[0];
        float conv = lscal[1];
        if (blockIdx.x == 0) {
            if (tid < 128) slot_out[tid] = lmu[tid];
            if (tid == 0) { slot_out[128] = mm; slot_out[129] = conv; }
        }
        tfm = fmaxf(1.f - mm, EPSV);
        if (frozen && j != 15) return;  // nothing new to compute
    }

    const bool first = (j == 0);
    const bool dovar = (j == 15);
    float4 mur[4];
    if (j > 0) {
        const float4* lmu4 = (const float4*)lmu;
#pragma unroll
        for (int k = 0; k < 4; ++k) mur[k] = lmu4[k * 8 + sub];
    } else {
#pragma unroll
        for (int k = 0; k < 4; ++k) mur[k] = make_float4(0.f, 0.f, 0.f, 0.f);
    }
    float4 acc[4];
#pragma unroll
    for (int k = 0; k < 4; ++k) acc[k] = make_float4(0.f, 0.f, 0.f, 0.f);
    float accA = 0.f, accV = 0.f;

    for (int row = gid; row < N; row += gstride) {
        float4 xv[4];
        if (!first && use16) {
            const uint2* xbr = xb + (size_t)row * 32;
#pragma unroll
            for (int k = 0; k < 4; ++k) {
                uint2 u = xbr[k * 8 + sub];
                xv[k].x = lo_bf16(u.x); xv[k].y = hi_bf16(u.x);
                xv[k].z = lo_bf16(u.y); xv[k].w = hi_bf16(u.y);
            }
        } else {
            const float4* xr = (const float4*)(x + (size_t)row * 128);
#pragma unroll
            for (int k = 0; k < 4; ++k) xv[k] = xr[k * 8 + sub];
            if (first && use16) {
                uint2* xbr = xb + (size_t)row * 32;
#pragma unroll
                for (int k = 0; k < 4; ++k) {
                    uint2 u;
                    u.x = pack2_bf16(xv[k].x, xv[k].y);
                    u.y = pack2_bf16(xv[k].z, xv[k].w);
                    xbr[k * 8 + sub] = u;
                }
            }
        }
        float dp = 0.f, np = 0.f;
#pragma unroll
        for (int k = 0; k < 4; ++k) {
            dp += mur[k].x * xv[k].x + mur[k].y * xv[k].y + mur[k].z * xv[k].z + mur[k].w * xv[k].w;
            np += xv[k].x * xv[k].x + xv[k].y * xv[k].y + xv[k].z * xv[k].z + xv[k].w * xv[k].w;
        }
        float d = first ? 0.f : qsum8(dp);
        float X2 = qsum8(np);
        // m = mobius_add(-mu, x) = (-A*mu + B*x)/den
        float A = 1.f - 2.f * d + X2;
        float B = 1.f - mm;
        float den = fmaxf(1.f - 2.f * d + mm * X2, EPSV);
        float iv = 1.f / den;
        float m2 = (A * A * mm - 2.f * A * B * d + B * B * X2) * iv * iv;
        float n = sqrtf(fmaxf(m2, EPSV));
        float at = fast_atanh(fminf(n, BALLC));
        float s = tfm * at / n;
        accA += s * (-A * iv);
        float delta = s * (B * iv);
        if (dovar) accV += 4.f * at * at;  // dist^2 = (2 atanh n)^2
#pragma unroll
        for (int k = 0; k < 4; ++k) {
            acc[k].x += delta * xv[k].x;
            acc[k].y += delta * xv[k].y;
            acc[k].z += delta * xv[k].z;
            acc[k].w += delta * xv[k].w;
        }
    }

    // sum across the 8 groups of each wave (xor bits 3..5)
#pragma unroll
    for (int m = 8; m < 64; m <<= 1) {
#pragma unroll
        for (int k = 0; k < 4; ++k) {
            acc[k].x += __shfl_xor(acc[k].x, m);
            acc[k].y += __shfl_xor(acc[k].y, m);
            acc[k].z += __shfl_xor(acc[k].z, m);
            acc[k].w += __shfl_xor(acc[k].w, m);
        }
        accA += __shfl_xor(accA, m);
        if (dovar) accV += __shfl_xor(accV, m);
    }
    if (lane < 8) {
#pragma unroll
        for (int k = 0; k < 4; ++k) {
            int c = (k * 8 + lane) * 4;
            lvec[wv][c + 0] = acc[k].x;
            lvec[wv][c + 1] = acc[k].y;
            lvec[wv][c + 2] = acc[k].z;
            lvec[wv][c + 3] = acc[k].w;
        }
    }
    if (lane == 0) { lalpha[wv] = accA; lv2[wv] = accV; }
    __syncthreads();
    if (tid < 128) {
        float s = 0.f;
#pragma unroll
        for (int i = 0; i < 16; ++i) s += lvec[i][tid];
        part[(size_t)blockIdx.x * 132 + tid] = s;
    }
    if (tid == 0) {
        float a = 0.f, v2s = 0.f;
#pragma unroll
        for (int i = 0; i < 16; ++i) { a += lalpha[i]; v2s += lv2[i]; }
        part[(size_t)blockIdx.x * 132 + 128] = a;
        if (dovar) alpha2[blockIdx.x] = v2s;
    }
}

// all threads execute; broadcasts lred[0]
#define TREE(val, outv)                                      \
    if (tid < 128) lred[tid] = (val);                        \
    __syncthreads();                                         \
    for (int off = 64; off >= 1; off >>= 1) {                \
        if (tid < off) lred[tid] += lred[tid + off];         \
        __syncthreads();                                     \
    }                                                        \
    outv = lred[0];                                          \
    __syncthreads();

// final mu update + variance finalize + p/q/Gram prep (1 block)
__global__ __launch_bounds__(1024) void k_fin(
        const float* __restrict__ mpar, const float* __restrict__ vpar,
        float* __restrict__ ws, const float* __restrict__ part,
        const float* __restrict__ alpha2, const int nblk, const float invN) {
    __shared__ float lvec[8][128];
    __shared__ float lred[128];
    __shared__ __align__(16) float lmu[128];
    __shared__ float lscal[2];
    const int tid = threadIdx.x;
    const float* slot_in = ws + SLOT1;  // pass 15 wrote M_14 here (15&1 == 1)
    if (slot_in[129] != 0.f) {
        if (tid < 128) lmu[tid] = slot_in[tid];
        if (tid == 0) lscal[0] = slot_in[128];
        __syncthreads();
    } else {
        mu_update_w0(part, nblk, invN, slot_in, true,
                     (float(*)[128])lvec, lmu, lscal, tid);
    }
    float mm = lscal[0];
    float av = 0.f;
    if (tid < 128)
        for (int b = tid; b < nblk; b += 128) av += alpha2[b];
    float varsum; TREE(av, varsum);
    float input_var = varsum * invN;
    float mpv = (tid < 128) ? mpar[tid] : 0.f;
    float mpn2; TREE(mpv * mpv, mpn2);
    float pn = sqrtf(fmaxf(mpn2, EPSV));
    float p_c = fast_tanh(pn) * mpv / pn;
    float pp; TREE(p_c * p_c, pp);
    float mu_c = (tid < 128) ? lmu[tid] : 0.f;
    float pm; TREE(p_c * mu_c, pm);
    float A = 1.f - 2.f * pm + mm;
    float B = 1.f - pp;
    float den = fmaxf(1.f - 2.f * pm + pp * mm, EPSV);
    float q_c = (B * mu_c - A * p_c) / den;
    float qq; TREE(q_c * q_c, qq);
    float mq; TREE(mu_c * q_c, mq);
    float pq; TREE(p_c * q_c, pq);
    float tfm = fmaxf(1.f - mm, EPSV);
    float tfp = fmaxf(1.f - pp, EPSV);
    float lam_p = 2.f / tfp;
    float svar = sqrtf(vpar[0] / (input_var + 1e-6f));
    float ks = (tfp / tfm) * svar;
    if (tid < 128) {
        ws[MUF + tid] = lmu[tid];
        ws[PF + tid] = p_c;
        ws[QF + tid] = q_c;
    }
    if (tid == 0) {
        float* sc = ws + SCF;
        sc[C_MM] = mm; sc[C_PP] = pp; sc[C_QQ] = qq; sc[C_MP] = pm;
        sc[C_MQ] = mq; sc[C_PQ] = pq; sc[C_TFM] = tfm; sc[C_LAMP] = lam_p;
        sc[C_KS] = ks;
    }
}

// out_i = expmap(p, ks * gyr(p,-mu, logmap(mu,x_i))); span{mu,p,q,x} closed form
__global__ __launch_bounds__(BTO) void k_out(const float* __restrict__ x,
                                             float* __restrict__ out,
                                             const float* __restrict__ ws,
                                             const int N) {
    const float* sc = ws + SCF;
    const float mm = sc[C_MM], pp = sc[C_PP], qq = sc[C_QQ];
    const float smp = sc[C_MP], smq = sc[C_MQ], spq = sc[C_PQ];
    const float tfm = sc[C_TFM], lam_p = sc[C_LAMP], ks = sc[C_KS];
    const int tid = threadIdx.x;
    const int lane = tid & 63;
    const int sub = lane & 7;
    const int gid = blockIdx.x * (BTO / 8) + (tid >> 3);
    const int gstride = gridDim.x * (BTO / 8);
    const float4* mu4 = (const float4*)(ws + MUF);
    const float4* p4 = (const float4*)(ws + PF);
    const float4* qv4 = (const float4*)(ws + QF);
    float4 mur[4], pr[4], qr[4];
#pragma unroll
    for (int k = 0; k < 4; ++k) {
        mur[k] = mu4[k * 8 + sub];
        pr[k] = p4[k * 8 + sub];
        qr[k] = qv4[k * 8 + sub];
    }
    for (int row = gid; row < N; row += gstride) {
        const float4* xr = (const float4*)(x + (size_t)row * 128);
        float4 xv[4];
#pragma unroll
        for (int k = 0; k < 4; ++k) xv[k] = xr[k * 8 + sub];
        float am = 0.f, ap = 0.f, aq = 0.f, an = 0.f;
#pragma unroll
        for (int k = 0; k < 4; ++k) {
            am += mur[k].x * xv[k].x + mur[k].y * xv[k].y + mur[k].z * xv[k].z + mur[k].w * xv[k].w;
            ap += pr[k].x * xv[k].x + pr[k].y * xv[k].y + pr[k].z * xv[k].z + pr[k].w * xv[k].w;
            aq += qr[k].x * xv[k].x + qr[k].y * xv[k].y + qr[k].z * xv[k].z + qr[k].w * xv[k].w;
            an += xv[k].x * xv[k].x + xv[k].y * xv[k].y + xv[k].z * xv[k].z + xv[k].w * xv[k].w;
        }
        float Dm = qsum8(am), Dp = qsum8(ap), Dq = qsum8(aq), X2 = qsum8(an);

        float A = 1.f - 2.f * Dm + X2;
        float B = 1.f - mm;
        float den = fmaxf(1.f - 2.f * Dm + mm * X2, EPSV);
        float iv = 1.f / den;
        float m_cm = -A * iv, m_cx = B * iv;
        float m_dm = (-A * mm + B * Dm) * iv;
        float m_dp = (-A * smp + B * Dp) * iv;
        float m_dq = (-A * smq + B * Dq) * iv;
        float m_n2 = (A * A * mm - 2.f * A * B * Dm + B * B * X2) * iv * iv;

        float n1 = sqrtf(fmaxf(m_n2, EPSV));
        float s1 = tfm * fast_atanh(fminf(n1, BALLC)) / n1;
        float t_cm = s1 * m_cm, t_cx = s1 * m_cx;
        float t_dm = s1 * m_dm, t_dp = s1 * m_dp, t_dq = s1 * m_dq;
        float t_n2 = s1 * s1 * m_n2;

        float xy = -t_dm, y2 = t_n2;
        A = 1.f + 2.f * xy + y2;
        B = 1.f - mm;
        den = fmaxf(1.f + 2.f * xy + mm * y2, EPSV);
        iv = 1.f / den;
        float w_cm = (-A + B * t_cm) * iv;
        float w_cx = B * t_cx * iv;
        float w_dp = (-A * smp + B * t_dp) * iv;
        float w_dq = (-A * smq + B * t_dq) * iv;
        float w_n2 = (A * A * mm + 2.f * A * B * xy + B * B * y2) * iv * iv;

        xy = w_dp; y2 = w_n2;
        A = 1.f + 2.f * xy + y2;
        B = 1.f - pp;
        den = fmaxf(1.f + 2.f * xy + pp * y2, EPSV);
        iv = 1.f / den;
        float w2_cm = B * w_cm * iv;
        float w2_cp = A * iv;
        float w2_cx = B * w_cx * iv;
        float w2_dp = (A * pp + B * w_dp) * iv;
        float w2_dq = (A * spq + B * w_dq) * iv;
        float w2_n2 = (A * A * pp + 2.f * A * B * xy + B * B * y2) * iv * iv;

        xy = w2_dq; y2 = w2_n2;
        A = 1.f + 2.f * xy + y2;
        B = 1.f - qq;
        den = fmaxf(1.f + 2.f * xy + qq * y2, EPSV);
        iv = 1.f / den;
        float w3_cm = B * w2_cm * iv;
        float w3_cp = B * w2_cp * iv;
        float w3_cq = A * iv;
        float w3_cx = B * w2_cx * iv;
        float w3_dp = (A * spq + B * w2_dp) * iv;
        float w3_n2 = (A * A * qq + 2.f * A * B * xy + B * B * y2) * iv * iv;

        float u_n2 = ks * ks * w3_n2;
        float nu = sqrtf(fmaxf(u_n2, EPSV));
        float arg = fminf(fmaxf(lam_p * nu * 0.5f, -MAXT), MAXT);
        float sf = fast_tanh(arg) * ks / nu;
        float s_cm = sf * w3_cm, s_cp = sf * w3_cp, s_cq = sf * w3_cq, s_cx = sf * w3_cx;
        float s_dp = sf * w3_dp;
        float s_n2 = sf * sf * w3_n2;

        xy = s_dp; y2 = s_n2;
        A = 1.f + 2.f * xy + y2;
        B = 1.f - pp;
        den = fmaxf(1.f + 2.f * xy + pp * y2, EPSV);
        iv = 1.f / den;
        float o_cm = B * s_cm * iv;
        float o_cp = (A + B * s_cp) * iv;
        float o_cq = B * s_cq * iv;
        float o_cx = B * s_cx * iv;

        float4* orow = (float4*)(out + (size_t)row * 128);
#pragma unroll
        for (int k = 0; k < 4; ++k) {
            float4 mk = mur[k], pk = pr[k], qk = qr[k], xk = xv[k];
            float4 ov;
            ov.x = o_cm * mk.x + o_cp * pk.x + o_cq * qk.x + o_cx * xk.x;
            ov.y = o_cm * mk.y + o_cp * pk.y + o_cq * qk.y + o_cx * xk.y;
            ov.z = o_cm * mk.z + o_cp * pk.z + o_cq * qk.z + o_cx * xk.z;
            ov.w = o_cm * mk.w + o_cp * pk.w + o_cq * qk.w + o_cx * xk.w;
            orow[k * 8 + sub] = ov;
        }
    }
}

extern "C" void kernel_launch(void* const* d_in, const int* in_sizes, int n_in,
                              void* d_out, int out_size, void* d_ws, size_t ws_size,
                              hipStream_t stream) {
    const float* x = (const float*)d_in[0];
    const float* mpar = (const float*)d_in[1];
    const float* vpar = (const float*)d_in[2];
    float* out = (float*)d_out;
    float* ws = (float*)d_ws;
    int N = in_sizes[0] / 128;
    float invN = 1.f / (float)N;

    long wsf = (long)(ws_size / sizeof(float));
    float* part = ws + PART;
    float* alpha2 = ws + ALPHA2;
    uint2* xb = (uint2*)(ws + XBOFF);
    int use16 = (wsf >= (long)XBOFF + (long)N * 64) ? 1 : 0;

    hipLaunchKernelGGL(k_zero, dim3(1), dim3(64), 0, stream, ws);
    for (int j = 0; j < 16; ++j)
        hipLaunchKernelGGL(k_pass, dim3(NBP), dim3(BTP), 0, stream,
                           x, xb, ws, part, alpha2, N, invN, j, use16);
    hipLaunchKernelGGL(k_fin, dim3(1), dim3(1024), 0, stream,
                       mpar, vpar, ws, part, alpha2, NBP, invN);
    hipLaunchKernelGGL(k_out, dim3(NBO), dim3(BTO), 0, stream, x, out, ws, N);
}